// Round 1
// baseline (75.205 us; speedup 1.0000x reference)
//
#include <hip/hip_runtime.h>

#define N_RAY 131072
#define NS 128
#define BIG_DELTA 1e10f
#define EPS 1e-10f

// One 64-lane wave per ray; lane l owns samples 2l and 2l+1 (contiguous ->
// float2 coalesced loads). Exclusive cumprod via wave-level shfl_up scan of
// per-lane pair products; reductions via shfl_down butterfly.
__global__ __launch_bounds__(256) void volrender_kernel(
    const float* __restrict__ rgb,
    const float* __restrict__ sigma,
    const float* __restrict__ z_vals,
    const int* __restrict__ wb_flag,
    float* __restrict__ out)
{
    const int tid  = blockIdx.x * blockDim.x + threadIdx.x;
    const int ray  = tid >> 6;
    const int lane = tid & 63;
    if (ray >= N_RAY) return;

    const int base = ray * NS;

    float2 z  = *reinterpret_cast<const float2*>(&z_vals[base + 2 * lane]);
    float2 sg = *reinterpret_cast<const float2*>(&sigma [base + 2 * lane]);

    // deltas
    float z_next = __shfl_down(z.x, 1);                 // z[2l+2] (lanes < 63)
    float d0 = z.y - z.x;
    float d1 = (lane == 63) ? BIG_DELTA : (z_next - z.y);

    // alpha = 1 - exp(-delta * relu(sigma))
    float a0 = 1.0f - expf(-d0 * fmaxf(sg.x, 0.0f));
    float a1 = 1.0f - expf(-d1 * fmaxf(sg.y, 0.0f));

    // transmittance terms
    float t0 = 1.0f - a0 + EPS;
    float t1 = 1.0f - a1 + EPS;

    // inclusive scan of pair products across the wave
    float p = t0 * t1;
    #pragma unroll
    for (int d = 1; d < 64; d <<= 1) {
        float q = __shfl_up(p, d);
        if (lane >= d) p *= q;
    }
    // exclusive
    float e = __shfl_up(p, 1);
    if (lane == 0) e = 1.0f;

    // weights
    float w0 = a0 * e;
    float w1 = a1 * (e * t0);

    // weights output: after comp_rgb(3N) + depth(N) + opacity(N)
    float* wout = out + (size_t)N_RAY * 5 + base;
    *reinterpret_cast<float2*>(&wout[2 * lane]) = make_float2(w0, w1);

    // rgb: 6 contiguous floats per lane at ray*384 + 6*lane (8B aligned)
    const float* rp = rgb + (size_t)ray * (NS * 3) + 6 * lane;
    float2 c01 = *reinterpret_cast<const float2*>(rp);
    float2 c23 = *reinterpret_cast<const float2*>(rp + 2);
    float2 c45 = *reinterpret_cast<const float2*>(rp + 4);

    // sample 2l rgb = (c01.x, c01.y, c23.x); sample 2l+1 rgb = (c23.y, c45.x, c45.y)
    float r   = w0 * c01.x + w1 * c23.y;
    float g   = w0 * c01.y + w1 * c45.x;
    float b   = w0 * c23.x + w1 * c45.y;
    float dep = w0 * z.x   + w1 * z.y;
    float op  = w0 + w1;

    // wave reduction (within 64-lane wave)
    #pragma unroll
    for (int d = 32; d > 0; d >>= 1) {
        r   += __shfl_down(r, d);
        g   += __shfl_down(g, d);
        b   += __shfl_down(b, d);
        dep += __shfl_down(dep, d);
        op  += __shfl_down(op, d);
    }

    if (lane == 0) {
        const int wb = *wb_flag;
        const float add = wb ? (1.0f - op) : 0.0f;
        out[(size_t)ray * 3 + 0] = r + add;
        out[(size_t)ray * 3 + 1] = g + add;
        out[(size_t)ray * 3 + 2] = b + add;
        out[(size_t)N_RAY * 3 + ray] = dep;
        out[(size_t)N_RAY * 4 + ray] = op;
    }
}

extern "C" void kernel_launch(void* const* d_in, const int* in_sizes, int n_in,
                              void* d_out, int out_size, void* d_ws, size_t ws_size,
                              hipStream_t stream) {
    const float* rgb    = (const float*)d_in[0];
    const float* sigma  = (const float*)d_in[1];
    const float* z_vals = (const float*)d_in[2];
    const int*   wb     = (const int*)d_in[3];
    float* out = (float*)d_out;

    // 4 rays per 256-thread block (1 wave per ray)
    const int blocks = N_RAY / 4;
    volrender_kernel<<<blocks, 256, 0, stream>>>(rgb, sigma, z_vals, wb, out);
}